// Round 2
// baseline (1104.013 us; speedup 1.0000x reference)
//
#include <hip/hip_runtime.h>
#include <math.h>

// Problem shape (fixed by setup_inputs): [B=16, C=3, T=600, H=72, W=72] fp32.
#define HW_ELEMS 5184              // 72*72 floats per (b,c,t) slab
#define NT       600
#define NC       3
#define NB       16
#define NSLABS   (NB * NC * NT)    // 28800 slabs
#define SLABS_PER_BLOCK 4          // one slab per wave, 4 waves/block
#define NBLOCKS  (NSLABS / SLABS_PER_BLOCK)   // 7200
#define BLOCKS_PER_BATCH (NBLOCKS / NB)       // 450

typedef float f4 __attribute__((ext_vector_type(4)));

// Self-resetting per-batch completion counters. Module device globals are
// zero-initialized at load and are NOT part of d_ws, so the harness poison
// fill cannot corrupt them. The projecting (last) block resets its counter
// before kernel end, so every complete execution leaves them at 0.
__device__ unsigned int g_cnt[NB];

// ---------------------------------------------------------------------------
// Fused kernel.
// Phase 1 (all 7200 blocks): spatial mean. One wave per slab; block covers 4
// consecutive slabs = 81 KB contiguous. Nontemporal float4 loads: the input
// is streamed exactly once with zero reuse, so skipping L2/L3 allocation
// avoids evicting the 2.39 GB poison fill's dirty lines during our read
// window (suspected cause of the observed 1.6 TB/s effective read BW).
// Phase 2 (last block per batch, detected via device-scope atomic): 3x3
// Gram matrix in double, dominant eigenvector by repeated squaring, project,
// write out[b, :]. Overlaps with phase-1 work of other batches.
// ---------------------------------------------------------------------------
__global__ __launch_bounds__(256) void fused_kernel(const float* __restrict__ in,
                                                    float* __restrict__ xbar,
                                                    float* __restrict__ out) {
    const int lane = threadIdx.x & 63;
    const int wid  = threadIdx.x >> 6;
    const int slab = blockIdx.x * SLABS_PER_BLOCK + wid;  // one slab per wave
    const int b    = blockIdx.x / BLOCKS_PER_BATCH;       // batch of this block

    // ---- phase 1: mean over 5184 floats = 1296 float4 = 20*64 + 16 ----
    const f4* __restrict__ p = (const f4*)(in + (size_t)slab * HW_ELEMS);
    float s0 = 0.f, s1 = 0.f;
    #pragma unroll
    for (int i = 0; i < 20; i += 2) {
        f4 a = __builtin_nontemporal_load(p + (i << 6) + lane);
        f4 c = __builtin_nontemporal_load(p + ((i + 1) << 6) + lane);
        s0 += (a.x + a.y) + (a.z + a.w);
        s1 += (c.x + c.y) + (c.z + c.w);
    }
    if (lane < 16) {
        f4 v = __builtin_nontemporal_load(p + 1280 + lane);
        s0 += (v.x + v.y) + (v.z + v.w);
    }
    float s = s0 + s1;
    #pragma unroll
    for (int off = 32; off; off >>= 1)
        s += __shfl_xor(s, off, 64);
    if (lane == 0) xbar[slab] = s * (1.0f / (float)HW_ELEMS);

    // ---- handoff: canonical block-completion signal (device scope) ----
    // __syncthreads() drains all waves' xbar stores (vmcnt(0) before barrier,
    // L1 is write-through -> stores are in this XCD's L2). tid0's
    // __threadfence() then releases the whole L2 at device scope.
    __shared__ int is_last;
    __syncthreads();
    if (threadIdx.x == 0) {
        __threadfence();
        unsigned int old = atomicAdd(&g_cnt[b], 1u);
        is_last = (old == BLOCKS_PER_BATCH - 1) ? 1 : 0;
    }
    __syncthreads();
    if (!is_last) return;          // block-uniform: no divergent-sync hazard
    __threadfence();               // acquire: invalidate before reading xbar

    // ---- phase 2: projection for batch b (256 threads) ----
    __shared__ float  sx[NC][NT];      // 7200 B
    __shared__ double red[6][256];     // 12288 B
    __shared__ float  S[3];

    const float* xb = xbar + b * (NC * NT);
    for (int i = threadIdx.x; i < NC * NT; i += 256)
        ((float*)sx)[i] = xb[i];
    __syncthreads();

    double g0 = 0, g1 = 0, g2 = 0, g3 = 0, g4 = 0, g5 = 0;
    for (int t = threadIdx.x; t < NT; t += 256) {
        double x0 = (double)sx[0][t];
        double x1 = (double)sx[1][t];
        double x2 = (double)sx[2][t];
        g0 += x0 * x0; g1 += x0 * x1; g2 += x0 * x2;
        g3 += x1 * x1; g4 += x1 * x2; g5 += x2 * x2;
    }
    red[0][threadIdx.x] = g0; red[1][threadIdx.x] = g1; red[2][threadIdx.x] = g2;
    red[3][threadIdx.x] = g3; red[4][threadIdx.x] = g4; red[5][threadIdx.x] = g5;
    __syncthreads();
    for (int st = 128; st > 0; st >>= 1) {
        if (threadIdx.x < st) {
            #pragma unroll
            for (int k = 0; k < 6; k++)
                red[k][threadIdx.x] += red[k][threadIdx.x + st];
        }
        __syncthreads();
    }

    if (threadIdx.x == 0) {
        double M[3][3] = {{red[0][0], red[1][0], red[2][0]},
                          {red[1][0], red[3][0], red[4][0]},
                          {red[2][0], red[4][0], red[5][0]}};
        // Repeated squaring with trace normalization: M -> (M/tr(M))^2.
        // Eigen-ratio squares each step -> machine precision in <=40 steps.
        for (int it = 0; it < 40; it++) {
            double tr = M[0][0] + M[1][1] + M[2][2];
            double inv = (tr > 0.0) ? (1.0 / tr) : 1.0;
            double T[3][3];
            #pragma unroll
            for (int i = 0; i < 3; i++)
                #pragma unroll
                for (int j = 0; j < 3; j++) T[i][j] = M[i][j] * inv;
            #pragma unroll
            for (int i = 0; i < 3; i++)
                #pragma unroll
                for (int j = 0; j < 3; j++) {
                    double acc = 0.0;
                    #pragma unroll
                    for (int k = 0; k < 3; k++) acc += T[i][k] * T[k][j];
                    M[i][j] = acc;
                }
        }
        // M ~= v v^T; take the column with the largest diagonal (= v_j^2).
        int jm = 0;
        if (M[1][1] > M[jm][jm]) jm = 1;
        if (M[2][2] > M[jm][jm]) jm = 2;
        double v0 = M[0][jm], v1 = M[1][jm], v2 = M[2][jm];
        double nrm = sqrt(v0 * v0 + v1 * v1 + v2 * v2);
        double inv = (nrm > 0.0) ? (1.0 / nrm) : 0.0;
        S[0] = (float)(v0 * inv);
        S[1] = (float)(v1 * inv);
        S[2] = (float)(v2 * inv);
    }
    __syncthreads();

    const float c0 = S[0], c1 = S[1], c2 = S[2];
    for (int t = threadIdx.x; t < NT; t += 256) {
        float x0 = sx[0][t], x1 = sx[1][t], x2 = sx[2][t];
        float d = c0 * x0 + c1 * x1 + c2 * x2;
        out[b * NT + t] = x1 - c1 * d;   // (P x)[1] = x1 - S1 * (S.x)
    }

    // self-reset for the next timed iteration / rocprof replay
    if (threadIdx.x == 0) g_cnt[b] = 0;
}

extern "C" void kernel_launch(void* const* d_in, const int* in_sizes, int n_in,
                              void* d_out, int out_size, void* d_ws, size_t ws_size,
                              hipStream_t stream) {
    const float* batch_x = (const float*)d_in[0];
    float* out  = (float*)d_out;   // [B, T] = 9600 floats
    float* xbar = (float*)d_ws;    // [B, C, T] = 28800 floats scratch

    fused_kernel<<<NBLOCKS, 256, 0, stream>>>(batch_x, xbar, out);
}